// Round 1
// baseline (19669.609 us; speedup 1.0000x reference)
//
#include <hip/hip_runtime.h>
#include <hip/hip_bf16.h>
#include <math.h>

// ESN: T=512 steps of h = tanh(x_t @ W_ih^T + h @ W_hh^T + b)
// T=512, B=64, I=128, H=1024. out = [512][64][1024] fp32 then h_final [64][1024].
//
// Persistent-kernel design, 256 WGs x 256 threads (one per CU), custom
// device-scope grid barrier (needs only co-residency: grid == #CUs, tiny
// LDS/VGPR -> all 256 WGs resident; no cooperative launch required).
//
// Partition: lane = output column j (64 per wave); WG = (jblk 0..15) x (bgrp
// 0..15, 4 batches each); 4 waves = 4 K-slices of 256 over the recurrent dot,
// + 4 slices of 32 over the input dot. LDS reduce, then coalesced NT store of
// out[t][b][j] (lane-contiguous in j).

#define T_STEPS 512
#define BATCH   64
#define HDIM    1024
#define IDIM    128
#define NWG     256

__device__ __forceinline__ void grid_barrier(unsigned* bar, unsigned target, int tid) {
    __syncthreads();   // all waves' stores drained (vmcnt 0) before arrive
    if (tid == 0) {
        // release: buffer_wbl2 pushes this XCD's dirty h lines to coherence pt
        unsigned prev = __hip_atomic_fetch_add(&bar[0], 1u, __ATOMIC_ACQ_REL,
                                               __HIP_MEMORY_SCOPE_AGENT);
        if (prev == NWG - 1u) {
            __hip_atomic_store(&bar[0], 0u, __ATOMIC_RELAXED, __HIP_MEMORY_SCOPE_AGENT);
            __hip_atomic_store(&bar[32], target, __ATOMIC_RELEASE, __HIP_MEMORY_SCOPE_AGENT);
        } else {
            // acquire on exit load: buffer_inv so stale h lines are dropped
            while (__hip_atomic_load(&bar[32], __ATOMIC_ACQUIRE,
                                     __HIP_MEMORY_SCOPE_AGENT) < target) {
                __builtin_amdgcn_s_sleep(1);
            }
        }
    }
    __syncthreads();
}

// src[R][C] -> dst[C][R], 64x64 LDS tiles, grid = (C/64)*(R/64), 256 thr
__global__ void transpose_f32(const float* __restrict__ src, float* __restrict__ dst,
                              int R, int C) {
    __shared__ float tile[64][65];
    const int tcol = threadIdx.x & 63;
    const int trow = threadIdx.x >> 6;
    const int nbx = C >> 6;
    const int bx = blockIdx.x % nbx;
    const int by = blockIdx.x / nbx;
    const int c0 = bx << 6, r0 = by << 6;
    for (int i = trow; i < 64; i += 4)
        tile[i][tcol] = src[(size_t)(r0 + i) * C + c0 + tcol];
    __syncthreads();
    for (int i = trow; i < 64; i += 4)
        dst[(size_t)(c0 + i) * R + r0 + tcol] = tile[tcol][i];
}

__global__ __launch_bounds__(256) void esn_persistent(
    const float* __restrict__ x,      // [512][64][128]
    const float* __restrict__ h0,     // [64][1024]
    const float* __restrict__ w_ihT,  // [128][1024]
    const float* __restrict__ w_hhT,  // [1024][1024]
    const float* __restrict__ bias,   // [1024]
    float* __restrict__ out,          // [512][64][1024]
    float* __restrict__ hfin,         // [64][1024]
    float* hA, float* hB,             // hT buffers: [1024 k][64 b]
    unsigned* bar)
{
    const int tid  = threadIdx.x;
    const int wg   = blockIdx.x;       // 0..255
    const int wave = tid >> 6;         // 0..3  (K-slice, then reduce role bi)
    const int lane = tid & 63;
    const int jblk = wg >> 4;          // 0..15
    const int bgrp = wg & 15;          // 0..15
    const int b0   = bgrp << 2;        // 4 batches per WG
    const int j    = (jblk << 6) + lane;

    __shared__ float red[4 * 256];     // [kslice][bi][lane]
    __shared__ float vals[256];        // [bi][lane] post-tanh

    // init hT(A) from h0: hA[k*64+b] = h0[b*1024+k]  (one elem per thread)
    {
        int f = (wg << 8) + tid;       // 0..65535
        int k = f >> 6, b = f & 63;
        hA[f] = h0[(size_t)b * HDIM + k];
    }
    unsigned target = 1;
    grid_barrier(bar, target++, tid);

    const float* hcur = hA;
    float* hnxt = hB;

    for (int t = 0; t < T_STEPS; ++t) {
        float a0 = 0.f, a1 = 0.f, a2 = 0.f, a3 = 0.f;
        // recurrent dot over this wave's K-slice of 256
        {
            const int k0 = wave << 8;
            const float* wc = w_hhT + (size_t)k0 * HDIM + j;   // coalesced over lanes
            const float* hr = hcur + (k0 << 6) + b0;           // same 16B all lanes
            #pragma unroll 8
            for (int k = 0; k < 256; ++k) {
                float wv = wc[(size_t)k * HDIM];
                float4 h4 = *(const float4*)(hr + (k << 6));
                a0 = fmaf(wv, h4.x, a0);
                a1 = fmaf(wv, h4.y, a1);
                a2 = fmaf(wv, h4.z, a2);
                a3 = fmaf(wv, h4.w, a3);
            }
        }
        // input dot: 128 k2 split 32 per wave
        {
            const int k20 = wave << 5;
            const float* wi = w_ihT + (size_t)k20 * HDIM + j;  // coalesced
            const float* xr = x + (size_t)t * (BATCH * IDIM) + k20;
            #pragma unroll 8
            for (int k2 = 0; k2 < 32; ++k2) {
                float wv = wi[(size_t)k2 * HDIM];
                float x0 = xr[(b0 + 0) * IDIM + k2];
                float x1 = xr[(b0 + 1) * IDIM + k2];
                float x2 = xr[(b0 + 2) * IDIM + k2];
                float x3 = xr[(b0 + 3) * IDIM + k2];
                a0 = fmaf(wv, x0, a0);
                a1 = fmaf(wv, x1, a1);
                a2 = fmaf(wv, x2, a2);
                a3 = fmaf(wv, x3, a3);
            }
        }
        {
            const int base = wave << 8;
            red[base + lane]       = a0;
            red[base + 64 + lane]  = a1;
            red[base + 128 + lane] = a2;
            red[base + 192 + lane] = a3;
        }
        __syncthreads();
        // this thread now handles (batch bi = wave, column j)
        float s = red[(0 << 8) + (wave << 6) + lane]
                + red[(1 << 8) + (wave << 6) + lane]
                + red[(2 << 8) + (wave << 6) + lane]
                + red[(3 << 8) + (wave << 6) + lane];
        s += bias[j];
        float hv = tanhf(s);
        size_t orow = ((size_t)t * BATCH + b0 + wave) * HDIM + j;
        __builtin_nontemporal_store(hv, out + orow);           // coalesced in j
        vals[(wave << 6) + lane] = hv;
        if (t == T_STEPS - 1)
            __builtin_nontemporal_store(hv, hfin + (size_t)(b0 + wave) * HDIM + j);
        __syncthreads();
        if (wave == 0) {  // pack hT for next step: hnxt[j*64 + b0..b0+3]
            float4 p;
            p.x = vals[lane];
            p.y = vals[64 + lane];
            p.z = vals[128 + lane];
            p.w = vals[192 + lane];
            *(float4*)(hnxt + ((size_t)j << 6) + b0) = p;
        }
        if (t != T_STEPS - 1)
            grid_barrier(bar, target++, tid);
        float* tmp = (float*)hcur; hcur = hnxt; hnxt = tmp;
    }
}

extern "C" void kernel_launch(void* const* d_in, const int* in_sizes, int n_in,
                              void* d_out, int out_size, void* d_ws, size_t ws_size,
                              hipStream_t stream) {
    const float* x    = (const float*)d_in[0];
    const float* h0   = (const float*)d_in[1];
    const float* w_ih = (const float*)d_in[2];   // [1024][128]
    const float* w_hh = (const float*)d_in[3];   // [1024][1024]
    const float* bias = (const float*)d_in[4];   // [1024]
    float* out = (float*)d_out;

    char* ws = (char*)d_ws;
    float* w_hhT  = (float*)ws;                              // 4 MB   [1024][1024]
    float* w_ihT  = (float*)(ws + 4194304);                  // 512 KB [128][1024]
    float* hA     = (float*)(ws + 4194304 + 524288);         // 256 KB [1024][64]
    float* hB     = hA + (HDIM * BATCH);                     // 256 KB
    unsigned* bar = (unsigned*)(ws + 4194304 + 524288 + 2 * 262144);  // 256 B

    hipMemsetAsync(bar, 0, 256, stream);
    transpose_f32<<<256, 256, 0, stream>>>(w_hh, w_hhT, HDIM, HDIM);
    transpose_f32<<<32, 256, 0, stream>>>(w_ih, w_ihT, HDIM, IDIM);
    esn_persistent<<<NWG, 256, 0, stream>>>(x, h0, w_ihT, w_hhT, bias,
                                            out, out + (size_t)T_STEPS * BATCH * HDIM,
                                            hA, hB, bar);
}

// Round 2
// 9996.439 us; speedup vs baseline: 1.9677x; 1.9677x over previous
//
#include <hip/hip_runtime.h>
#include <hip/hip_bf16.h>
#include <math.h>

// ESN: 512 sequential steps of h = tanh([h | x_t] @ [W_hh|W_ih]^T + b)
// T=512, B=64, I=128, H=1024, K' = 1024+128 = 1152.
//
// R2 design:
//  * 256 persistent WGs (1/CU), WG = jblk(16, 64 j) x bgrp(16, 4 b).
//    XCD-swizzled: xcd = wg&7 owns 2 jblks -> its W slice (590 KB) is
//    L2-resident; W streamed from L2 each step, fully coalesced from a
//    transposed WT[k][j] layout ([1152][1024] fp32, built once in ws).
//  * h rows for step t are read straight from out[t-1] (no h buffers);
//    staged with x_t into LDS (18.4 KB) once per step.
//  * wave = batch b; lane = (p = k-quarter, jq = j-quad). Thread: 4 j x 1 b
//    x 288 k = 1152 FMA; __shfl_xor(16/32) reduces over p.
//  * Barrier: per-WG arrive flags on distinct 128B lines (release store);
//    WG0 gathers via sc0/sc1 bypass-loads (no L1/L2 invalidation -> W stays
//    warm); single release flag; ONE acquire (buffer_inv) per WG per step.

#define T_STEPS 512
#define BATCH   64
#define HDIM    1024
#define IDIM    128
#define KDIM    1152
#define NWG     256

// Coherent read that bypasses L1/L2 without invalidating them.
__device__ __forceinline__ unsigned sc_load(const unsigned* p) {
    unsigned v;
    asm volatile("global_load_dword %0, %1, off sc0 sc1\n\ts_waitcnt vmcnt(0)"
                 : "=v"(v) : "v"(p) : "memory");
    return v;
}

__device__ __forceinline__ void grid_barrier(unsigned* flags, unsigned* rel,
                                             int wg, int tid, unsigned tgt) {
    __syncthreads();   // all waves done reading LDS + issued their stores
    if (tid == 0) {
        // release: orders this WG's out-row stores before the flag
        __hip_atomic_store(&flags[wg * 32], tgt, __ATOMIC_RELEASE,
                           __HIP_MEMORY_SCOPE_AGENT);
    }
    if (wg == 0) {
        // 256 threads poll 256 distinct lines in parallel, invalidation-free
        while (sc_load(&flags[tid * 32]) < tgt) {}
        __syncthreads();
        if (tid == 0)
            __hip_atomic_store(rel, tgt, __ATOMIC_RELEASE,
                               __HIP_MEMORY_SCOPE_AGENT);
    }
    if (tid == 0) {
        while (sc_load(rel) < tgt) {}
        // exactly one acquire per WG per step: buffer_inv so h rows are seen
        (void)__hip_atomic_load(rel, __ATOMIC_ACQUIRE, __HIP_MEMORY_SCOPE_AGENT);
    }
    __syncthreads();
}

// src[R][C] -> dst[C][R], 64x64 LDS tiles, grid = (C/64)*(R/64), 256 thr
__global__ void transpose_f32(const float* __restrict__ src, float* __restrict__ dst,
                              int R, int C) {
    __shared__ float tile[64][65];
    const int tcol = threadIdx.x & 63;
    const int trow = threadIdx.x >> 6;
    const int nbx = C >> 6;
    const int bx = blockIdx.x % nbx;
    const int by = blockIdx.x / nbx;
    const int c0 = bx << 6, r0 = by << 6;
    for (int i = trow; i < 64; i += 4)
        tile[i][tcol] = src[(size_t)(r0 + i) * C + c0 + tcol];
    __syncthreads();
    for (int i = trow; i < 64; i += 4)
        dst[(size_t)(c0 + i) * R + r0 + tcol] = tile[tcol][i];
}

__global__ __launch_bounds__(256, 1) void esn_persistent(
    const float* __restrict__ x,     // [512][64][128]
    const float* __restrict__ h0,    // [64][1024]
    const float* __restrict__ WT,    // [1152][1024]  rows 0..1023 = w_hh^T, 1024.. = w_ih^T
    const float* __restrict__ bias,  // [1024]
    float* __restrict__ out,         // [512][64][1024]
    float* __restrict__ hfin,        // [64][1024]
    unsigned* flags, unsigned* rel)
{
    const int tid = threadIdx.x;
    const int wg  = blockIdx.x;
    // XCD swizzle: wg&7 = xcd (round-robin dispatch heuristic); 2 jblks/XCD
    const int slot = wg >> 3;
    const int jblk = ((wg & 7) << 1) | (slot & 1);   // 0..15
    const int bgrp = slot >> 1;                      // 0..15
    const int wv   = tid >> 6;                       // 0..3
    const int lane = tid & 63;
    const int p    = lane >> 4;                      // k-quarter 0..3
    const int jq   = lane & 15;                      // j-quad
    const int b    = (bgrp << 2) | wv;               // batch 0..63
    const int j0   = (jblk << 6) + (jq << 2);        // first of 4 j's

    __shared__ float ht[4][KDIM];                    // [wave's batch][k]

    const float4 bias4 = *(const float4*)(bias + j0);
    const int kbase = p * 288;

    for (int t = 0; t < T_STEPS; ++t) {
        // ---- stage [h_{t-1} | x_t] row b into LDS (coalesced) ----
        const float* hrow = t ? (out + ((size_t)(t - 1) * BATCH + b) * HDIM)
                              : (h0 + (size_t)b * HDIM);
        const float* xrow = x + ((size_t)t * BATCH + b) * IDIM;
        #pragma unroll
        for (int i = 0; i < 4; ++i)
            *(float4*)&ht[wv][(i << 8) + (lane << 2)] =
                *(const float4*)(hrow + (i << 8) + (lane << 2));
        if (lane < 32)
            *(float4*)&ht[wv][HDIM + (lane << 2)] = *(const float4*)(xrow + (lane << 2));
        __syncthreads();

        // ---- compute: acc[j0..j0+3] over this thread's 288-k quarter ----
        float4 acc = make_float4(0.f, 0.f, 0.f, 0.f);
        const float* wp = WT + (size_t)kbase * HDIM + j0;  // W row stride 1024
        const float* hp = &ht[wv][kbase];
        #pragma unroll 8
        for (int i = 0; i < 72; ++i) {
            float4 h4 = *(const float4*)(hp + (i << 2));
            const float* wk = wp + ((size_t)i << 12);      // i*4*1024
            float4 w0 = *(const float4*)(wk);
            float4 w1 = *(const float4*)(wk + 1024);
            float4 w2 = *(const float4*)(wk + 2048);
            float4 w3 = *(const float4*)(wk + 3072);
            acc.x = fmaf(w0.x, h4.x, acc.x);
            acc.y = fmaf(w0.y, h4.x, acc.y);
            acc.z = fmaf(w0.z, h4.x, acc.z);
            acc.w = fmaf(w0.w, h4.x, acc.w);
            acc.x = fmaf(w1.x, h4.y, acc.x);
            acc.y = fmaf(w1.y, h4.y, acc.y);
            acc.z = fmaf(w1.z, h4.y, acc.z);
            acc.w = fmaf(w1.w, h4.y, acc.w);
            acc.x = fmaf(w2.x, h4.z, acc.x);
            acc.y = fmaf(w2.y, h4.z, acc.y);
            acc.z = fmaf(w2.z, h4.z, acc.z);
            acc.w = fmaf(w2.w, h4.z, acc.w);
            acc.x = fmaf(w3.x, h4.w, acc.x);
            acc.y = fmaf(w3.y, h4.w, acc.y);
            acc.z = fmaf(w3.z, h4.w, acc.z);
            acc.w = fmaf(w3.w, h4.w, acc.w);
        }
        // reduce the 4 k-quarters (lanes p*16+jq: xor 16, then 32)
        acc.x += __shfl_xor(acc.x, 16); acc.x += __shfl_xor(acc.x, 32);
        acc.y += __shfl_xor(acc.y, 16); acc.y += __shfl_xor(acc.y, 32);
        acc.z += __shfl_xor(acc.z, 16); acc.z += __shfl_xor(acc.z, 32);
        acc.w += __shfl_xor(acc.w, 16); acc.w += __shfl_xor(acc.w, 32);

        if (p == 0) {
            float4 o;
            o.x = tanhf(acc.x + bias4.x);
            o.y = tanhf(acc.y + bias4.y);
            o.z = tanhf(acc.z + bias4.z);
            o.w = tanhf(acc.w + bias4.w);
            *(float4*)(out + ((size_t)t * BATCH + b) * HDIM + j0) = o;
            if (t == T_STEPS - 1)
                *(float4*)(hfin + (size_t)b * HDIM + j0) = o;
        }

        if (t != T_STEPS - 1)
            grid_barrier(flags, rel, wg, tid, (unsigned)(t + 1));
    }
}

extern "C" void kernel_launch(void* const* d_in, const int* in_sizes, int n_in,
                              void* d_out, int out_size, void* d_ws, size_t ws_size,
                              hipStream_t stream) {
    const float* x    = (const float*)d_in[0];
    const float* h0   = (const float*)d_in[1];
    const float* w_ih = (const float*)d_in[2];   // [1024][128]
    const float* w_hh = (const float*)d_in[3];   // [1024][1024]
    const float* bias = (const float*)d_in[4];   // [1024]
    float* out = (float*)d_out;

    char* ws = (char*)d_ws;
    float*    WT    = (float*)ws;                         // [1152][1024] = 4.72 MB
    unsigned* flags = (unsigned*)(ws + 4718592);          // 256 x 128 B
    unsigned* rel   = (unsigned*)(ws + 4718592 + 32768);  // 128 B

    hipMemsetAsync(flags, 0, 32768 + 128, stream);
    // WT[k][j] = w_hh[j][k]  (rows 0..1023)
    transpose_f32<<<256, 256, 0, stream>>>(w_hh, WT, HDIM, HDIM);
    // WT[1024+k2][j] = w_ih[j][k2]  (rows 1024..1151)
    transpose_f32<<<32, 256, 0, stream>>>(w_ih, WT + (size_t)HDIM * HDIM, HDIM, IDIM);
    esn_persistent<<<NWG, 256, 0, stream>>>(x, h0, WT, bias,
                                            out, out + (size_t)T_STEPS * BATCH * HDIM,
                                            flags, rel);
}

// Round 3
// 6613.323 us; speedup vs baseline: 2.9742x; 1.5116x over previous
//
#include <hip/hip_runtime.h>
#include <hip/hip_bf16.h>
#include <math.h>

// ESN: 512 sequential steps of h = tanh([h | x_t] @ [W_hh|W_ih]^T + b)
// T=512, B=64, I=128, H=1024, K' = 1152.
//
// R3: 256 persistent WGs (1/CU) x 512 threads (8 waves, 2/SIMD).
//  * WG = jblk(32 j) x bgrp(8 b). XCD-swizzled: xcd owns 4 jblks -> 590 KB
//    W slice L2-resident. W read ONCE per WG per step (147 KB), k-split
//    across the 8 waves (144 k each) -> every W element serves all 8 batches.
//  * lane = ksub(8) x jq(8): thread = 4 j x 8 b x ~18 k. k handled in
//    float4 chunks interleaved by ksub (conflict-free LDS broadcast reads).
//  * h_{t-1} rows come straight from out[t-2... t-1]; staged with x_t into
//    LDS row-major (coalesced, conflict-free).
//  * reduce: __shfl_xor over ksub (8/16/32), then padded-LDS cross-wave sum.
//  * barrier: R2's proven flags + sc0/sc1 bypass-poll design (1 acquire/WG).

#define T_STEPS 512
#define BATCH   64
#define HDIM    1024
#define IDIM    128
#define KDIM    1152
#define NWG     256
#define NJ      32
#define NB      8

__device__ __forceinline__ unsigned sc_load(const unsigned* p) {
    unsigned v;
    asm volatile("global_load_dword %0, %1, off sc0 sc1\n\ts_waitcnt vmcnt(0)"
                 : "=v"(v) : "v"(p) : "memory");
    return v;
}

__device__ __forceinline__ void grid_barrier(unsigned* flags, unsigned* rel,
                                             int wg, int tid, unsigned tgt) {
    __syncthreads();
    if (tid == 0)
        __hip_atomic_store(&flags[wg * 32], tgt, __ATOMIC_RELEASE,
                           __HIP_MEMORY_SCOPE_AGENT);
    if (wg == 0) {
        if (tid < NWG)
            while (sc_load(&flags[tid * 32]) < tgt) {}
        __syncthreads();
        if (tid == 0)
            __hip_atomic_store(rel, tgt, __ATOMIC_RELEASE,
                               __HIP_MEMORY_SCOPE_AGENT);
    }
    if (tid == 0) {
        while (sc_load(rel) < tgt) {}
        (void)__hip_atomic_load(rel, __ATOMIC_ACQUIRE, __HIP_MEMORY_SCOPE_AGENT);
    }
    __syncthreads();
}

// src[R][C] -> dst[C][R], 64x64 LDS tiles, grid = (C/64)*(R/64), 256 thr
__global__ void transpose_f32(const float* __restrict__ src, float* __restrict__ dst,
                              int R, int C) {
    __shared__ float tile[64][65];
    const int tcol = threadIdx.x & 63;
    const int trow = threadIdx.x >> 6;
    const int nbx = C >> 6;
    const int bx = blockIdx.x % nbx;
    const int by = blockIdx.x / nbx;
    const int c0 = bx << 6, r0 = by << 6;
    for (int i = trow; i < 64; i += 4)
        tile[i][tcol] = src[(size_t)(r0 + i) * C + c0 + tcol];
    __syncthreads();
    for (int i = trow; i < 64; i += 4)
        dst[(size_t)(c0 + i) * R + r0 + tcol] = tile[tcol][i];
}

__global__ __launch_bounds__(512) void esn_persistent(
    const float* __restrict__ x,     // [512][64][128]
    const float* __restrict__ h0,    // [64][1024]
    const float* __restrict__ WT,    // [1152][1024]
    const float* __restrict__ bias,  // [1024]
    float* __restrict__ out,         // [512][64][1024]
    float* __restrict__ hfin,        // [64][1024]
    unsigned* flags, unsigned* rel)
{
    const int tid  = threadIdx.x;
    const int wg   = blockIdx.x;
    const int wave = tid >> 6;                       // 0..7 (k-slice / stage-row)
    const int lane = tid & 63;
    const int jq   = lane & 7;                       // 4 j each -> 32 j
    const int ksub = lane >> 3;                      // 0..7 k-interleave
    // XCD swizzle: xcd = wg&7 owns jblks 4x..4x+3 (W slice 590 KB, L2-resident)
    const int jblk = ((wg & 7) << 2) | ((wg >> 3) & 3);  // 0..31
    const int bgrp = wg >> 5;                            // 0..7
    const int b0   = bgrp << 3;
    const int j0   = (jblk << 5) + (jq << 2);
    const int wbase = wave * 144;

    __shared__ float  ht[NB][KDIM];                  // 36.9 KB, row-major
    __shared__ float4 red[8 * 8 * 9];                // [w][jq] stride 9, +b (padded)

    for (int t = 0; t < T_STEPS; ++t) {
        // ---- stage [h_{t-1} | x_t] row (b0+wave) into LDS, coalesced ----
        const float* hrow = t ? (out + ((size_t)(t - 1) * BATCH + b0 + wave) * HDIM)
                              : (h0 + (size_t)(b0 + wave) * HDIM);
        const float* xrow = x + ((size_t)t * BATCH + b0 + wave) * IDIM;
        #pragma unroll
        for (int i = 0; i < 4; ++i)
            *(float4*)&ht[wave][(i << 8) + (lane << 2)] =
                *(const float4*)(hrow + (i << 8) + (lane << 2));
        if (lane < 32)
            *(float4*)&ht[wave][HDIM + (lane << 2)] = *(const float4*)(xrow + (lane << 2));
        __syncthreads();

        // ---- compute: acc[b].xyzw = partial sums for j0..j0+3, this wave's k ----
        float4 acc[NB];
        #pragma unroll
        for (int bb = 0; bb < NB; ++bb) acc[bb] = make_float4(0.f, 0.f, 0.f, 0.f);

        // 36 float4-chunks per wave; chunk c = 8i + ksub (i=0..3 all, i=4 ksub<4)
        #pragma unroll
        for (int i = 0; i < 5; ++i) {
            if (i == 4 && ksub >= 4) break;
            const int k = wbase + ((i << 3) + ksub) << 2 >> 0;  // (wbase + (8i+ksub)*4)
            const int kk = wbase + (((i << 3) + ksub) << 2);
            (void)k;
            const float* wk = WT + (size_t)kk * HDIM + j0;
            float4 w0 = *(const float4*)(wk);
            float4 w1 = *(const float4*)(wk + HDIM);
            float4 w2 = *(const float4*)(wk + 2 * HDIM);
            float4 w3 = *(const float4*)(wk + 3 * HDIM);
            #pragma unroll
            for (int bb = 0; bb < NB; ++bb) {
                float4 h4 = *(const float4*)&ht[bb][kk];
                acc[bb].x = fmaf(w0.x, h4.x, acc[bb].x);
                acc[bb].y = fmaf(w0.y, h4.x, acc[bb].y);
                acc[bb].z = fmaf(w0.z, h4.x, acc[bb].z);
                acc[bb].w = fmaf(w0.w, h4.x, acc[bb].w);
                acc[bb].x = fmaf(w1.x, h4.y, acc[bb].x);
                acc[bb].y = fmaf(w1.y, h4.y, acc[bb].y);
                acc[bb].z = fmaf(w1.z, h4.y, acc[bb].z);
                acc[bb].w = fmaf(w1.w, h4.y, acc[bb].w);
                acc[bb].x = fmaf(w2.x, h4.z, acc[bb].x);
                acc[bb].y = fmaf(w2.y, h4.z, acc[bb].y);
                acc[bb].z = fmaf(w2.z, h4.z, acc[bb].z);
                acc[bb].w = fmaf(w2.w, h4.z, acc[bb].w);
                acc[bb].x = fmaf(w3.x, h4.w, acc[bb].x);
                acc[bb].y = fmaf(w3.y, h4.w, acc[bb].y);
                acc[bb].z = fmaf(w3.z, h4.w, acc[bb].z);
                acc[bb].w = fmaf(w3.w, h4.w, acc[bb].w);
            }
        }

        // ---- reduce over ksub (lane bits 3,4,5) ----
        #pragma unroll
        for (int bb = 0; bb < NB; ++bb) {
            acc[bb].x += __shfl_xor(acc[bb].x, 8);
            acc[bb].y += __shfl_xor(acc[bb].y, 8);
            acc[bb].z += __shfl_xor(acc[bb].z, 8);
            acc[bb].w += __shfl_xor(acc[bb].w, 8);
            acc[bb].x += __shfl_xor(acc[bb].x, 16);
            acc[bb].y += __shfl_xor(acc[bb].y, 16);
            acc[bb].z += __shfl_xor(acc[bb].z, 16);
            acc[bb].w += __shfl_xor(acc[bb].w, 16);
            acc[bb].x += __shfl_xor(acc[bb].x, 32);
            acc[bb].y += __shfl_xor(acc[bb].y, 32);
            acc[bb].z += __shfl_xor(acc[bb].z, 32);
            acc[bb].w += __shfl_xor(acc[bb].w, 32);
        }
        if (ksub == 0) {
            #pragma unroll
            for (int bb = 0; bb < NB; ++bb)
                red[((wave << 3) + jq) * 9 + bb] = acc[bb];
        }
        __syncthreads();

        // ---- cross-wave sum + tanh + store (64 threads) ----
        if (tid < 64) {
            const int bb  = tid >> 3;
            const int jq2 = tid & 7;
            float4 s = make_float4(0.f, 0.f, 0.f, 0.f);
            #pragma unroll
            for (int w = 0; w < 8; ++w) {
                float4 r = red[((w << 3) + jq2) * 9 + bb];
                s.x += r.x; s.y += r.y; s.z += r.z; s.w += r.w;
            }
            const int jj = (jblk << 5) + (jq2 << 2);
            const float4 b4 = *(const float4*)(bias + jj);
            float4 o;
            o.x = tanhf(s.x + b4.x);
            o.y = tanhf(s.y + b4.y);
            o.z = tanhf(s.z + b4.z);
            o.w = tanhf(s.w + b4.w);
            *(float4*)(out + ((size_t)t * BATCH + b0 + bb) * HDIM + jj) = o;
            if (t == T_STEPS - 1)
                *(float4*)(hfin + (size_t)(b0 + bb) * HDIM + jj) = o;
        }

        if (t != T_STEPS - 1)
            grid_barrier(flags, rel, wg, tid, (unsigned)(t + 1));
    }
}

extern "C" void kernel_launch(void* const* d_in, const int* in_sizes, int n_in,
                              void* d_out, int out_size, void* d_ws, size_t ws_size,
                              hipStream_t stream) {
    const float* x    = (const float*)d_in[0];
    const float* h0   = (const float*)d_in[1];
    const float* w_ih = (const float*)d_in[2];   // [1024][128]
    const float* w_hh = (const float*)d_in[3];   // [1024][1024]
    const float* bias = (const float*)d_in[4];   // [1024]
    float* out = (float*)d_out;

    char* ws = (char*)d_ws;
    float*    WT    = (float*)ws;                         // [1152][1024] = 4.72 MB
    unsigned* flags = (unsigned*)(ws + 4718592);          // 256 x 128 B
    unsigned* rel   = (unsigned*)(ws + 4718592 + 32768);  // 128 B

    hipMemsetAsync(flags, 0, 32768 + 128, stream);
    transpose_f32<<<256, 256, 0, stream>>>(w_hh, WT, HDIM, HDIM);
    transpose_f32<<<32, 256, 0, stream>>>(w_ih, WT + (size_t)HDIM * HDIM, HDIM, IDIM);
    esn_persistent<<<NWG, 512, 0, stream>>>(x, h0, WT, bias,
                                            out, out + (size_t)T_STEPS * BATCH * HDIM,
                                            flags, rel);
}

// Round 4
// 6091.600 us; speedup vs baseline: 3.2290x; 1.0856x over previous
//
#include <hip/hip_runtime.h>
#include <hip/hip_bf16.h>
#include <math.h>

// ESN: 512 sequential steps of h = tanh([h | x_t] @ [W_hh|W_ih]^T + b)
// T=512, B=64, I=128, H=1024, K' = 1152.
//
// R4: 256 persistent WGs (1/CU) x 512 threads (8 waves, 2/SIMD).
//  * NO cache invalidation anywhere: consumers read h rows (out[t-1]) via
//    sc0/sc1 bypass loads (coherence-point reads, L1/L2 untouched), producers
//    release-store their arrive flag (buffer_wbl2 pushes h to the coherence
//    point first). => W stays L2-resident for all 512 steps.
//  * Single-hop barrier: every WG polls all 256 per-WG flag lines directly
//    (256 threads x 1 line, bypass loads) -- one visibility round-trip.
//  * WG = jblk(32 j) x bgrp(8 b), XCD-swizzled (590 KB W slice per XCD L2).
//    8 waves split K': recurrent 1024k -> 4 uniform float4-chunks per
//    ksub-lane; x 128k -> float2 tail. All 18 W float4 loads hoisted.

#define T_STEPS 512
#define BATCH   64
#define HDIM    1024
#define IDIM    128
#define KDIM    1152
#define NWG     256
#define NB      8

__device__ __forceinline__ unsigned sc_load(const unsigned* p) {
    unsigned v;
    asm volatile("global_load_dword %0, %1, off sc0 sc1\n\ts_waitcnt vmcnt(0)"
                 : "=&v"(v) : "v"(p) : "memory");
    return v;
}

__device__ __forceinline__ void sc_load4x4(const float* p0, const float* p1,
                                           const float* p2, const float* p3,
                                           float4& a, float4& b,
                                           float4& c, float4& d) {
    asm volatile(
        "global_load_dwordx4 %0, %4, off sc0 sc1\n\t"
        "global_load_dwordx4 %1, %5, off sc0 sc1\n\t"
        "global_load_dwordx4 %2, %6, off sc0 sc1\n\t"
        "global_load_dwordx4 %3, %7, off sc0 sc1\n\t"
        "s_waitcnt vmcnt(0)"
        : "=&v"(a), "=&v"(b), "=&v"(c), "=&v"(d)
        : "v"(p0), "v"(p1), "v"(p2), "v"(p3)
        : "memory");
}

__device__ __forceinline__ void sc_load4(const float* p, float4& a) {
    asm volatile("global_load_dwordx4 %0, %1, off sc0 sc1\n\ts_waitcnt vmcnt(0)"
                 : "=&v"(a) : "v"(p) : "memory");
}

// Single-hop grid barrier: arrive = release store to own line; depart = all
// WGs poll all NWG lines with bypass loads (no L2 invalidation).
__device__ __forceinline__ void grid_barrier(unsigned* flags, int wg, int tid,
                                             unsigned tgt) {
    __syncthreads();   // every wave drains its out-stores (vmcnt 0) first
    if (tid == 0)
        __hip_atomic_store(&flags[wg * 32], tgt, __ATOMIC_RELEASE,
                           __HIP_MEMORY_SCOPE_AGENT);   // wbl2 + flag store
    if (tid < NWG)
        while (sc_load(&flags[tid * 32]) < tgt) {}
    __syncthreads();
}

// src[R][C] -> dst[C][R], 64x64 LDS tiles, grid = (C/64)*(R/64), 256 thr
__global__ void transpose_f32(const float* __restrict__ src, float* __restrict__ dst,
                              int R, int C) {
    __shared__ float tile[64][65];
    const int tcol = threadIdx.x & 63;
    const int trow = threadIdx.x >> 6;
    const int nbx = C >> 6;
    const int bx = blockIdx.x % nbx;
    const int by = blockIdx.x / nbx;
    const int c0 = bx << 6, r0 = by << 6;
    for (int i = trow; i < 64; i += 4)
        tile[i][tcol] = src[(size_t)(r0 + i) * C + c0 + tcol];
    __syncthreads();
    for (int i = trow; i < 64; i += 4)
        dst[(size_t)(c0 + i) * R + r0 + tcol] = tile[tcol][i];
}

__global__ __launch_bounds__(512) void esn_persistent(
    const float* __restrict__ x,     // [512][64][128]
    const float* __restrict__ h0,    // [64][1024]
    const float* __restrict__ WT,    // [1152][1024]
    const float* __restrict__ bias,  // [1024]
    float* __restrict__ out,         // [512][64][1024]
    float* __restrict__ hfin,        // [64][1024]
    unsigned* flags)
{
    const int tid  = threadIdx.x;
    const int wg   = blockIdx.x;
    const int wave = tid >> 6;                       // 0..7 (k-slice / stage-row)
    const int lane = tid & 63;
    const int jq   = lane & 7;                       // 4 j each -> 32 j
    const int ksub = lane >> 3;                      // 0..7 k-interleave
    const int jblk = ((wg & 7) << 2) | ((wg >> 3) & 3);  // XCD owns 4 jblks
    const int bgrp = wg >> 5;                            // 0..7
    const int b0   = bgrp << 3;
    const int j0   = (jblk << 5) + (jq << 2);
    const int krec = wave << 7;                      // recurrent k base (128/wave)
    const int kx   = HDIM + (wave << 4) + (ksub << 1);  // x-part rows (2 each)

    __shared__ float  ht[NB][KDIM];                  // 36.9 KB row-major
    __shared__ float4 red[8 * 8 * 9];                // [w][jq] stride 9, +b pad

    for (int t = 0; t < T_STEPS; ++t) {
        // ---- stage [h_{t-1} | x_t] row (b0+wave) into LDS via bypass loads ----
        const float* hrow = t ? (out + ((size_t)(t - 1) * BATCH + b0 + wave) * HDIM)
                              : (h0 + (size_t)(b0 + wave) * HDIM);
        {
            float4 a, b, c, d;
            const float* p = hrow + (lane << 2);
            sc_load4x4(p, p + 256, p + 512, p + 768, a, b, c, d);
            *(float4*)&ht[wave][(lane << 2)]       = a;
            *(float4*)&ht[wave][256 + (lane << 2)] = b;
            *(float4*)&ht[wave][512 + (lane << 2)] = c;
            *(float4*)&ht[wave][768 + (lane << 2)] = d;
        }
        if (lane < 32) {
            float4 xv;
            sc_load4(x + ((size_t)t * BATCH + b0 + wave) * IDIM + (lane << 2), xv);
            *(float4*)&ht[wave][HDIM + (lane << 2)] = xv;
        }
        __syncthreads();

        // ---- hoist all 18 W float4 loads (L2-resident) ----
        float4 Wv[18];
        {
            const float* wp = WT + (size_t)krec * HDIM + j0;
            #pragma unroll
            for (int i = 0; i < 4; ++i) {
                const int kk = ((i << 3) + ksub) << 2;      // 0..124 step 4
                const float* wk = wp + (size_t)kk * HDIM;
                Wv[i * 4 + 0] = *(const float4*)(wk);
                Wv[i * 4 + 1] = *(const float4*)(wk + HDIM);
                Wv[i * 4 + 2] = *(const float4*)(wk + 2 * HDIM);
                Wv[i * 4 + 3] = *(const float4*)(wk + 3 * HDIM);
            }
            const float* wkx = WT + (size_t)kx * HDIM + j0;
            Wv[16] = *(const float4*)(wkx);
            Wv[17] = *(const float4*)(wkx + HDIM);
        }

        // ---- FMA: acc[b] over this thread's k ----
        float4 acc[NB];
        #pragma unroll
        for (int bb = 0; bb < NB; ++bb) acc[bb] = make_float4(0.f, 0.f, 0.f, 0.f);

        #pragma unroll
        for (int i = 0; i < 4; ++i) {
            const int kk = krec + ((((i << 3) + ksub)) << 2);
            const float4 w0 = Wv[i * 4 + 0], w1 = Wv[i * 4 + 1];
            const float4 w2 = Wv[i * 4 + 2], w3 = Wv[i * 4 + 3];
            #pragma unroll
            for (int bb = 0; bb < NB; ++bb) {
                float4 h4 = *(const float4*)&ht[bb][kk];
                acc[bb].x = fmaf(w0.x, h4.x, acc[bb].x);
                acc[bb].y = fmaf(w0.y, h4.x, acc[bb].y);
                acc[bb].z = fmaf(w0.z, h4.x, acc[bb].z);
                acc[bb].w = fmaf(w0.w, h4.x, acc[bb].w);
                acc[bb].x = fmaf(w1.x, h4.y, acc[bb].x);
                acc[bb].y = fmaf(w1.y, h4.y, acc[bb].y);
                acc[bb].z = fmaf(w1.z, h4.y, acc[bb].z);
                acc[bb].w = fmaf(w1.w, h4.y, acc[bb].w);
                acc[bb].x = fmaf(w2.x, h4.z, acc[bb].x);
                acc[bb].y = fmaf(w2.y, h4.z, acc[bb].y);
                acc[bb].z = fmaf(w2.z, h4.z, acc[bb].z);
                acc[bb].w = fmaf(w2.w, h4.z, acc[bb].w);
                acc[bb].x = fmaf(w3.x, h4.w, acc[bb].x);
                acc[bb].y = fmaf(w3.y, h4.w, acc[bb].y);
                acc[bb].z = fmaf(w3.z, h4.w, acc[bb].z);
                acc[bb].w = fmaf(w3.w, h4.w, acc[bb].w);
            }
        }
        // x tail: 2 k per thread
        #pragma unroll
        for (int bb = 0; bb < NB; ++bb) {
            float2 hx = *(const float2*)&ht[bb][kx];
            acc[bb].x = fmaf(Wv[16].x, hx.x, acc[bb].x);
            acc[bb].y = fmaf(Wv[16].y, hx.x, acc[bb].y);
            acc[bb].z = fmaf(Wv[16].z, hx.x, acc[bb].z);
            acc[bb].w = fmaf(Wv[16].w, hx.x, acc[bb].w);
            acc[bb].x = fmaf(Wv[17].x, hx.y, acc[bb].x);
            acc[bb].y = fmaf(Wv[17].y, hx.y, acc[bb].y);
            acc[bb].z = fmaf(Wv[17].z, hx.y, acc[bb].z);
            acc[bb].w = fmaf(Wv[17].w, hx.y, acc[bb].w);
        }

        // ---- reduce over ksub (lane bits 3,4,5) ----
        #pragma unroll
        for (int bb = 0; bb < NB; ++bb) {
            acc[bb].x += __shfl_xor(acc[bb].x, 8);
            acc[bb].y += __shfl_xor(acc[bb].y, 8);
            acc[bb].z += __shfl_xor(acc[bb].z, 8);
            acc[bb].w += __shfl_xor(acc[bb].w, 8);
            acc[bb].x += __shfl_xor(acc[bb].x, 16);
            acc[bb].y += __shfl_xor(acc[bb].y, 16);
            acc[bb].z += __shfl_xor(acc[bb].z, 16);
            acc[bb].w += __shfl_xor(acc[bb].w, 16);
            acc[bb].x += __shfl_xor(acc[bb].x, 32);
            acc[bb].y += __shfl_xor(acc[bb].y, 32);
            acc[bb].z += __shfl_xor(acc[bb].z, 32);
            acc[bb].w += __shfl_xor(acc[bb].w, 32);
        }
        if (ksub == 0) {
            #pragma unroll
            for (int bb = 0; bb < NB; ++bb)
                red[((wave << 3) + jq) * 9 + bb] = acc[bb];
        }
        __syncthreads();

        // ---- cross-wave sum + tanh + store (64 threads) ----
        if (tid < 64) {
            const int bb  = tid >> 3;
            const int jq2 = tid & 7;
            float4 s = make_float4(0.f, 0.f, 0.f, 0.f);
            #pragma unroll
            for (int w = 0; w < 8; ++w) {
                float4 r = red[((w << 3) + jq2) * 9 + bb];
                s.x += r.x; s.y += r.y; s.z += r.z; s.w += r.w;
            }
            const int jj = (jblk << 5) + (jq2 << 2);
            const float4 b4 = *(const float4*)(bias + jj);
            float4 o;
            o.x = tanhf(s.x + b4.x);
            o.y = tanhf(s.y + b4.y);
            o.z = tanhf(s.z + b4.z);
            o.w = tanhf(s.w + b4.w);
            *(float4*)(out + ((size_t)t * BATCH + b0 + bb) * HDIM + jj) = o;
            if (t == T_STEPS - 1)
                *(float4*)(hfin + (size_t)(b0 + bb) * HDIM + jj) = o;
        }

        if (t != T_STEPS - 1)
            grid_barrier(flags, wg, tid, (unsigned)(t + 1));
    }
}

extern "C" void kernel_launch(void* const* d_in, const int* in_sizes, int n_in,
                              void* d_out, int out_size, void* d_ws, size_t ws_size,
                              hipStream_t stream) {
    const float* x    = (const float*)d_in[0];
    const float* h0   = (const float*)d_in[1];
    const float* w_ih = (const float*)d_in[2];   // [1024][128]
    const float* w_hh = (const float*)d_in[3];   // [1024][1024]
    const float* bias = (const float*)d_in[4];   // [1024]
    float* out = (float*)d_out;

    char* ws = (char*)d_ws;
    float*    WT    = (float*)ws;                // [1152][1024] = 4.72 MB
    unsigned* flags = (unsigned*)(ws + 4718592); // 256 x 128 B

    hipMemsetAsync(flags, 0, 32768, stream);
    transpose_f32<<<256, 256, 0, stream>>>(w_hh, WT, HDIM, HDIM);
    transpose_f32<<<32, 256, 0, stream>>>(w_ih, WT + (size_t)HDIM * HDIM, HDIM, IDIM);
    esn_persistent<<<NWG, 512, 0, stream>>>(x, h0, WT, bias,
                                            out, out + (size_t)T_STEPS * BATCH * HDIM,
                                            flags);
}